// Round 5
// baseline (149.772 us; speedup 1.0000x reference)
//
#include <hip/hip_runtime.h>
#include <hip/hip_bf16.h>

// Fused Asterisk block, round 4: pre-converted bf16 input in swizzled plane
// layout + global_load_lds staging + R=2 rows/block + 2-phase double buffer.
//
// Tap geometry (verified r0-r3), tap k, staged slot r' = base_r + l (l = local row):
//   g=0: base_r=2, dj=2k-4 | g=1: base_r=k, dj=0 | g=2: base_r=k, dj=4-2k
//   g=3: base_r=4-k, dj=2k-4
// Plane image (bf16 shorts, 4096 per (b,row,chunk) plane), padded col pc=col+4:
//   idx = (pc*32 + ((c>>3) ^ ((pc>>2)&3))*8 + (c&7)) ^ (((pc>>4)&1)<<5) - 128

typedef __attribute__((ext_vector_type(8))) __bf16 bf16x8;
typedef __attribute__((ext_vector_type(4))) float f32x4;

#define HH 128
#define WW 128
#define CIN 256
#define NCHUNK 8
#define CHUNK 32
#define COLS 136
#define TROWS 6
#define BUF_SHORTS (TROWS*COLS*CHUNK)   // 26112 shorts; dbuf = 104448 B
#define WPG (40*64*32)                  // 81920 bf16 per branch
#define XT_OFF (1u<<20)
#define XT_BYTES (8u*128u*8u*8192u)     // 67,108,864 B

__device__ __forceinline__ ushort f2bf(float f) {
    union { float f; unsigned u; } v; v.f = f;
    unsigned r = v.u + 0x7FFF + ((v.u >> 16) & 1);
    return (ushort)(r >> 16);
}

__device__ __forceinline__ void gll16(const void* g, const void* l) {
    __builtin_amdgcn_global_load_lds(
        (const __attribute__((address_space(1))) unsigned*)g,
        (__attribute__((address_space(3))) unsigned*)l, 16, 0, 0);
}

// wp[((g*40 + s)*64 + m)*32 + kk] = bf16( w_g[(m*256 + (s/5)*32 + kk)*5 + (s%5)] )
__global__ void repack_w(const float* __restrict__ w0, const float* __restrict__ w1,
                         const float* __restrict__ w2, const float* __restrict__ w3,
                         ushort* __restrict__ wp) {
    int idx = blockIdx.x * 256 + threadIdx.x;
    int g   = idx / WPG;
    int rem = idx - g * WPG;
    int s   = rem >> 11;
    int r2  = rem & 2047;
    int m   = r2 >> 5;
    int kk  = r2 & 31;
    int k   = s % 5;
    int cc  = s / 5;
    const float* w = (g == 0) ? w0 : (g == 1) ? w1 : (g == 2) ? w2 : w3;
    wp[idx] = f2bf(w[(m * CIN + cc * 32 + kk) * 5 + k]);
}

// x fp32 [b][c][row][col] -> xt bf16 planes [(b*128+row)*8+cc][4096] (swizzled image)
__global__ void prep_x(const float* __restrict__ x, ushort* __restrict__ xt) {
    int plane = blockIdx.x;              // ((b*128 + row)*8 + cc)
    int cc  = plane & 7;
    int row = (plane >> 3) & 127;
    int b   = plane >> 10;
    ushort* P = xt + (size_t)plane * 4096;
    const float* xb = x + (((size_t)b * CIN + cc * CHUNK) * HH + row) * WW;
    int t = threadIdx.x;
#pragma unroll
    for (int it = 0; it < 4; ++it) {
        int id  = t + it * 256;          // 0..1023
        int c   = (id >> 7) * 4;         // 0,4,...,28
        int col = id & 127;
        float f0 = xb[(size_t)(c + 0) * (HH*WW) + col];
        float f1 = xb[(size_t)(c + 1) * (HH*WW) + col];
        float f2 = xb[(size_t)(c + 2) * (HH*WW) + col];
        float f3 = xb[(size_t)(c + 3) * (HH*WW) + col];
        __hip_bfloat162 lo = __float22bfloat162_rn(make_float2(f0, f1));
        __hip_bfloat162 hi = __float22bfloat162_rn(make_float2(f2, f3));
        uint2 pk;
        pk.x = *(unsigned*)&lo;
        pk.y = *(unsigned*)&hi;
        int pc  = col + 4;
        int idx = pc * 32 + (((c >> 3) ^ ((pc >> 2) & 3)) * 8) + (c & 7);
        idx = (idx ^ (((pc >> 4) & 1) << 5)) - 128;
        *(uint2*)&P[idx] = pk;
    }
}

__global__ __launch_bounds__(512, 2)
void asterisk_mfma2(const ushort* __restrict__ xt,
                    const ushort* __restrict__ wp,
                    const float* __restrict__ b0, const float* __restrict__ b1,
                    const float* __restrict__ b2, const float* __restrict__ b3,
                    float* __restrict__ out) {
    __shared__ __align__(16) short xs[2][BUF_SHORTS];

    const int t    = threadIdx.x;
    const int lane = t & 63;
    const int wid  = t >> 6;        // 0..7
    const int g    = wid & 3;       // branch
    const int l    = wid >> 2;      // local row 0/1
    const int m16  = lane & 15;
    const int h    = lane >> 4;

    // XCD-bijective swizzle: batch = XCD (512 blocks, 512%8==0)
    int id = blockIdx.x;
    int sw = (id & 7) * 64 + (id >> 3);
    const int b  = sw >> 6;
    const int p  = sw & 63;
    const int i0 = 4 * (p >> 1) + (p & 1);   // first output row of the pair
    const int i  = i0 + 2 * l;               // this wave's output row

    // ---- zero pad columns (both buffers) ----
    for (int e = t; e < 2 * TROWS * 8 * CHUNK; e += 512) {
        int s    = e;
        int bufi = s >= TROWS * 8 * CHUNK;
        if (bufi) s -= TROWS * 8 * CHUNK;
        int r  = s >> 8;
        int pc = (s >> 5) & 7;
        int c  = s & 31;
        int col = (pc < 4) ? pc : 128 + pc;
        xs[bufi][(r * COLS + col) * CHUNK + c] = 0;
    }
    // ---- zero out-of-bounds row planes (both buffers; never re-written) ----
    for (int r = 0; r < TROWS; ++r) {
        int row = i0 + 2 * r - 4;
        if ((unsigned)row >= HH) {
            for (int e = t; e < 128 * CHUNK; e += 512) {
                xs[0][(r * COLS + 4) * CHUNK + e] = 0;
                xs[1][(r * COLS + 4) * CHUNK + e] = 0;
            }
        }
    }

    // ---- accumulators init = bias ----
    const float* bias = (g == 0) ? b0 : (g == 1) ? b1 : (g == 2) ? b2 : b3;
    f32x4 acc[4][8];
#pragma unroll
    for (int mb = 0; mb < 4; ++mb) {
        f32x4 bv;
#pragma unroll
        for (int rr = 0; rr < 4; ++rr) bv[rr] = bias[mb * 16 + h * 4 + rr];
#pragma unroll
        for (int nb = 0; nb < 8; ++nb) acc[mb][nb] = bv;
    }

    const ushort* wg = wp + (size_t)g * WPG;
    const size_t pbase = (size_t)b * 128 * 8;   // plane index base for this batch

    // ---- STAGE: copy 6 swizzled planes into buffer sel via global_load_lds ----
    auto stage = [&](int cc, int sel) {
#pragma unroll
        for (int r = 0; r < TROWS; ++r) {
            int row = i0 + 2 * r - 4;
            if ((unsigned)row < HH) {
                const ushort* gsrc = xt + (pbase + (size_t)row * 8 + cc) * 4096
                                        + wid * 512 + lane * 8;
                const short* ldst = &xs[sel][(r * COLS + 4) * CHUNK + wid * 512];
                gll16(gsrc, ldst);
            }
        }
    };

    stage(0, 0);
    __syncthreads();    // drains vmcnt(0): buf0 ready, zeros published

    for (int cc = 0; cc < NCHUNK; ++cc) {
        const int sel = cc & 1;
        if (cc < NCHUNK - 1) stage(cc + 1, sel ^ 1);   // issue loads first (T3)

        const short* xsel = xs[sel];
        const ushort* wc = wg + (size_t)(cc * 5 * 64 * 32) + m16 * 32 + h * 8;
        bf16x8 a_cur[4], a_nxt[4];
#pragma unroll
        for (int mb = 0; mb < 4; ++mb)
            a_cur[mb] = *(const bf16x8*)(wc + mb * 16 * 32);
#pragma unroll
        for (int k = 0; k < 5; ++k) {
            if (k < 4) {
                const ushort* wk1 = wc + (size_t)(k + 1) * 64 * 32;
#pragma unroll
                for (int mb = 0; mb < 4; ++mb)
                    a_nxt[mb] = *(const bf16x8*)(wk1 + mb * 16 * 32);
            }
            int rbase = (g == 0) ? 2 : (g == 3 ? 4 - k : k);
            int r  = rbase + l;
            int dj = (g == 1) ? 0 : (g == 2 ? 4 - 2 * k : 2 * k - 4);
            int col0 = m16 + dj + 4;
            int sl   = h ^ ((col0 >> 2) & 3);
            int base = (r * COLS + col0) * CHUNK + sl * 8;
            base ^= ((col0 >> 4) & 1) << 5;
#pragma unroll
            for (int nb = 0; nb < 8; ++nb) {
                int idx = (base + nb * 16 * CHUNK) ^ ((nb & 1) << 5);
                bf16x8 bf = *(const bf16x8*)(&xsel[idx]);
#pragma unroll
                for (int mb = 0; mb < 4; ++mb)
                    acc[mb][nb] = __builtin_amdgcn_mfma_f32_16x16x32_bf16(
                        a_cur[mb], bf, acc[mb][nb], 0, 0, 0);
            }
            if (k < 4) {
#pragma unroll
                for (int mb = 0; mb < 4; ++mb) a_cur[mb] = a_nxt[mb];
            }
        }
        __syncthreads();   // implicit vmcnt(0): next buffer staged & published
    }

    // ---- epilogue ----
    size_t obase = (((size_t)b * 256 + g * 64) * HH + i) * WW;
#pragma unroll
    for (int mb = 0; mb < 4; ++mb)
#pragma unroll
        for (int rr = 0; rr < 4; ++rr) {
            float* op = out + obase + (size_t)(mb * 16 + h * 4 + rr) * HH * WW + m16;
#pragma unroll
            for (int nb = 0; nb < 8; ++nb)
                op[nb * 16] = acc[mb][nb][rr];
        }
}

// ---------------- fallback (round-3 kernel) if ws too small ----------------
#define XS_ELEMS (5*COLS*CHUNK)
__global__ __launch_bounds__(256, 4)
void asterisk_mfma_fb(const float* __restrict__ x,
                      const ushort* __restrict__ wp,
                      const float* __restrict__ b0, const float* __restrict__ b1,
                      const float* __restrict__ b2, const float* __restrict__ b3,
                      float* __restrict__ out) {
    __shared__ __align__(16) short xs[XS_ELEMS];
    const int t    = threadIdx.x;
    const int lane = t & 63;
    const int wid  = t >> 6;
    const int m16  = lane & 15;
    const int h    = lane >> 4;
    int id = blockIdx.x;
    int sw = (id & 7) * 128 + (id >> 3);
    const int b = sw >> 7;
    const int i = sw & 127;
    for (int e = t; e < 5 * 8 * CHUNK; e += 256) {
        int r  = e >> 8;
        int pc = (e >> 5) & 7;
        int c  = e & 31;
        int col = (pc < 4) ? pc : 128 + pc;
        xs[(r * COLS + col) * CHUNK + c] = 0;
    }
    for (int r = 0; r < 5; ++r) {
        int row = i + 2 * r - 4;
        if ((unsigned)row >= HH)
            for (int e = t; e < COLS * CHUNK; e += 256)
                xs[r * COLS * CHUNK + e] = 0;
    }
    const float* bias = (wid == 0) ? b0 : (wid == 1) ? b1 : (wid == 2) ? b2 : b3;
    f32x4 acc[4][8];
#pragma unroll
    for (int mb = 0; mb < 4; ++mb) {
        f32x4 bv;
#pragma unroll
        for (int rr = 0; rr < 4; ++rr) bv[rr] = bias[mb * 16 + h * 4 + rr];
#pragma unroll
        for (int nb = 0; nb < 8; ++nb) acc[mb][nb] = bv;
    }
    const int cg = t >> 5;
    const int q  = t & 31;
    const float* xb = x + (size_t)b * CIN * HH * WW;
    const ushort* wg = wp + (size_t)wid * WPG;
    for (int cc = 0; cc < NCHUNK; ++cc) {
        __syncthreads();
        {
            int c0 = cc * CHUNK + cg * 4;
            int slot = cg >> 1;
            int sub  = (cg & 1) * 4;
            const float* srcc = xb + (size_t)c0 * HH * WW + q * 4;
#pragma unroll
            for (int r = 0; r < 5; ++r) {
                int row = i + 2 * r - 4;
                if ((unsigned)row < HH) {
                    const float* src = srcc + (size_t)row * WW;
                    float4 v0 = *(const float4*)(src);
                    float4 v1 = *(const float4*)(src + HH * WW);
                    float4 v2 = *(const float4*)(src + 2 * HH * WW);
                    float4 v3 = *(const float4*)(src + 3 * HH * WW);
#pragma unroll
                    for (int jj = 0; jj < 4; ++jj) {
                        int col = q * 4 + 4 + jj;
                        int sl  = slot ^ ((col >> 2) & 3);
                        float f0 = ((const float*)&v0)[jj];
                        float f1 = ((const float*)&v1)[jj];
                        float f2 = ((const float*)&v2)[jj];
                        float f3 = ((const float*)&v3)[jj];
                        __hip_bfloat162 lo = __float22bfloat162_rn(make_float2(f0, f1));
                        __hip_bfloat162 hi = __float22bfloat162_rn(make_float2(f2, f3));
                        uint2 pk;
                        pk.x = *(unsigned*)&lo;
                        pk.y = *(unsigned*)&hi;
                        int wi = (r * COLS + col) * CHUNK + sl * 8 + sub;
                        wi ^= ((col >> 4) & 1) << 5;
                        *(uint2*)&xs[wi] = pk;
                    }
                }
            }
        }
        __syncthreads();
        const ushort* wc = wg + (size_t)(cc * 5 * 64 * 32) + m16 * 32 + h * 8;
        bf16x8 a_cur[4], a_nxt[4];
#pragma unroll
        for (int mb = 0; mb < 4; ++mb)
            a_cur[mb] = *(const bf16x8*)(wc + mb * 16 * 32);
#pragma unroll
        for (int k = 0; k < 5; ++k) {
            if (k < 4) {
                const ushort* wk1 = wc + (size_t)(k + 1) * 64 * 32;
#pragma unroll
                for (int mb = 0; mb < 4; ++mb)
                    a_nxt[mb] = *(const bf16x8*)(wk1 + mb * 16 * 32);
            }
            int r  = (wid == 0) ? 2 : (wid == 3 ? 4 - k : k);
            int dj = (wid == 1) ? 0 : (wid == 2 ? 4 - 2 * k : 2 * k - 4);
            int col0 = m16 + dj + 4;
            int sl   = h ^ ((col0 >> 2) & 3);
            int base = (r * COLS + col0) * CHUNK + sl * 8;
            base ^= ((col0 >> 4) & 1) << 5;
#pragma unroll
            for (int nb = 0; nb < 8; ++nb) {
                int idx = (base + nb * 16 * CHUNK) ^ ((nb & 1) << 5);
                bf16x8 bf = *(const bf16x8*)(&xs[idx]);
#pragma unroll
                for (int mb = 0; mb < 4; ++mb)
                    acc[mb][nb] = __builtin_amdgcn_mfma_f32_16x16x32_bf16(
                        a_cur[mb], bf, acc[mb][nb], 0, 0, 0);
            }
            if (k < 4) {
#pragma unroll
                for (int mb = 0; mb < 4; ++mb) a_cur[mb] = a_nxt[mb];
            }
        }
    }
    size_t obase = (((size_t)b * 256 + wid * 64) * HH + i) * WW;
#pragma unroll
    for (int mb = 0; mb < 4; ++mb)
#pragma unroll
        for (int rr = 0; rr < 4; ++rr) {
            float* op = out + obase + (size_t)(mb * 16 + h * 4 + rr) * HH * WW + m16;
#pragma unroll
            for (int nb = 0; nb < 8; ++nb)
                op[nb * 16] = acc[mb][nb][rr];
        }
}

extern "C" void kernel_launch(void* const* d_in, const int* in_sizes, int n_in,
                              void* d_out, int out_size, void* d_ws, size_t ws_size,
                              hipStream_t stream) {
    const float* x    = (const float*)d_in[0];
    const float* w_h  = (const float*)d_in[1];
    const float* b_h  = (const float*)d_in[2];
    const float* w_v  = (const float*)d_in[3];
    const float* b_v  = (const float*)d_in[4];
    const float* w_d1 = (const float*)d_in[5];
    const float* b_d1 = (const float*)d_in[6];
    const float* w_d2 = (const float*)d_in[7];
    const float* b_d2 = (const float*)d_in[8];
    float* out = (float*)d_out;
    ushort* wpack = (ushort*)d_ws;

    repack_w<<<1280, 256, 0, stream>>>(w_h, w_v, w_d1, w_d2, wpack);

    if (ws_size >= (size_t)XT_OFF + (size_t)XT_BYTES) {
        ushort* xt = (ushort*)((char*)d_ws + XT_OFF);
        prep_x<<<8192, 256, 0, stream>>>(x, xt);
        asterisk_mfma2<<<512, 512, 0, stream>>>(xt, wpack, b_h, b_v, b_d1, b_d2, out);
    } else {
        asterisk_mfma_fb<<<1024, 256, 0, stream>>>(x, wpack, b_h, b_v, b_d1, b_d2, out);
    }
}

// Round 6
// 141.312 us; speedup vs baseline: 1.0599x; 1.0599x over previous
//
#include <hip/hip_runtime.h>
#include <hip/hip_bf16.h>

// Fused Asterisk block, round 6: coalesced prep (64B/thread col-block writes),
// prep+repack merged into one kernel, main kernel with linear A-prefetch.
//
// Tap geometry (verified r0-r5), tap k, staged slot r' = base_r + l (l = local row):
//   g=0: base_r=2, dj=2k-4 | g=1: base_r=k, dj=0 | g=2: base_r=k, dj=4-2k
//   g=3: base_r=4-k, dj=2k-4
// Plane image (bf16 shorts, 4096 per (b,row,chunk) plane), padded col pc=col+4:
//   idx = (pc*32 + ((c>>3) ^ ((pc>>2)&3))*8 + (c&7)) ^ (((pc>>4)&1)<<5) - 128
// Equivalent col-block form used by prep: block base (pc ^ ((pc>>4)&1))*32 - 128,
//   dst[o*8+j] = bf16(x[c]) with c = (o ^ ((pc>>2)&3))*8 + j.

typedef __attribute__((ext_vector_type(8))) __bf16 bf16x8;
typedef __attribute__((ext_vector_type(4))) float f32x4;

#define HH 128
#define WW 128
#define CIN 256
#define NCHUNK 8
#define CHUNK 32
#define COLS 136
#define TROWS 6
#define BUF_SHORTS (TROWS*COLS*CHUNK)   // 26112 shorts; dbuf = 104448 B
#define WPG (40*64*32)                  // 81920 bf16 per branch
#define XT_OFF (1u<<20)
#define XT_BYTES (8u*128u*8u*8192u)     // 67,108,864 B
#define PREP_BLOCKS 4096
#define REPACK_BLOCKS 160

__device__ __forceinline__ ushort f2bf(float f) {
    union { float f; unsigned u; } v; v.f = f;
    unsigned r = v.u + 0x7FFF + ((v.u >> 16) & 1);   // RNE
    return (ushort)(r >> 16);
}

__device__ __forceinline__ void gll16(const void* g, const void* l) {
    __builtin_amdgcn_global_load_lds(
        (const __attribute__((address_space(1))) unsigned*)g,
        (__attribute__((address_space(3))) unsigned*)l, 16, 0, 0);
}

// Merged prep: blocks [0,4096) convert x -> xt (swizzled plane image, 64B
// coalesced stores); blocks [4096,4256) repack weights:
// wp[((g*40+s)*64+m)*32+kk] = bf16( w_g[(m*256+(s/5)*32+kk)*5 + (s%5)] )
__global__ void prep_all(const float* __restrict__ x,
                         const float* __restrict__ w0, const float* __restrict__ w1,
                         const float* __restrict__ w2, const float* __restrict__ w3,
                         ushort* __restrict__ wp, ushort* __restrict__ xt) {
    if (blockIdx.x < PREP_BLOCKS) {
        int t     = threadIdx.x;
        int plane = blockIdx.x * 2 + (t >> 7);   // ((b*128 + row)*8 + cc)
        int col   = t & 127;
        int cc  = plane & 7;
        int row = (plane >> 3) & 127;
        int b   = plane >> 10;
        const float* xb = x + ((size_t)b * CIN + cc * CHUNK) * (HH * WW)
                            + (size_t)row * WW + col;
        int pc = col + 4;
        int s3 = (pc >> 2) & 3;
        uint4 vo[4];
#pragma unroll
        for (int o = 0; o < 4; ++o) {
            int ch = (o ^ s3) * 8;               // source channel octet
            ushort h0 = f2bf(xb[(size_t)(ch + 0) * (HH*WW)]);
            ushort h1 = f2bf(xb[(size_t)(ch + 1) * (HH*WW)]);
            ushort h2 = f2bf(xb[(size_t)(ch + 2) * (HH*WW)]);
            ushort h3 = f2bf(xb[(size_t)(ch + 3) * (HH*WW)]);
            ushort h4 = f2bf(xb[(size_t)(ch + 4) * (HH*WW)]);
            ushort h5 = f2bf(xb[(size_t)(ch + 5) * (HH*WW)]);
            ushort h6 = f2bf(xb[(size_t)(ch + 6) * (HH*WW)]);
            ushort h7 = f2bf(xb[(size_t)(ch + 7) * (HH*WW)]);
            vo[o].x = (unsigned)h0 | ((unsigned)h1 << 16);
            vo[o].y = (unsigned)h2 | ((unsigned)h3 << 16);
            vo[o].z = (unsigned)h4 | ((unsigned)h5 << 16);
            vo[o].w = (unsigned)h6 | ((unsigned)h7 << 16);
        }
        int pcx = pc ^ ((pc >> 4) & 1);          // bit5 pair-swap, whole block
        ushort* P = xt + (size_t)plane * 4096 + (pcx * 32 - 128);
        uint4* P4 = (uint4*)P;
        P4[0] = vo[0]; P4[1] = vo[1]; P4[2] = vo[2]; P4[3] = vo[3];
    } else {
        int tid2 = (blockIdx.x - PREP_BLOCKS) * 256 + threadIdx.x;  // 0..40959
#pragma unroll
        for (int e = 0; e < 8; ++e) {
            int idx = tid2 + e * (REPACK_BLOCKS * 256);   // 0..327679
            int g   = idx / WPG;
            int rem = idx - g * WPG;
            int s   = rem >> 11;
            int r2  = rem & 2047;
            int m   = r2 >> 5;
            int kk  = r2 & 31;
            int k   = s % 5;
            int cg  = s / 5;
            const float* w = (g == 0) ? w0 : (g == 1) ? w1 : (g == 2) ? w2 : w3;
            wp[idx] = f2bf(w[(m * CIN + cg * 32 + kk) * 5 + k]);
        }
    }
}

__global__ __launch_bounds__(512, 2)
void asterisk_mfma2(const ushort* __restrict__ xt,
                    const ushort* __restrict__ wp,
                    const float* __restrict__ b0, const float* __restrict__ b1,
                    const float* __restrict__ b2, const float* __restrict__ b3,
                    float* __restrict__ out) {
    __shared__ __align__(16) short xs[2][BUF_SHORTS];

    const int t    = threadIdx.x;
    const int lane = t & 63;
    const int wid  = t >> 6;        // 0..7
    const int g    = wid & 3;       // branch
    const int l    = wid >> 2;      // local row 0/1
    const int m16  = lane & 15;
    const int h    = lane >> 4;

    // XCD-bijective swizzle: batch = XCD (512 blocks, 512%8==0)
    int id = blockIdx.x;
    int sw = (id & 7) * 64 + (id >> 3);
    const int b  = sw >> 6;
    const int p  = sw & 63;
    const int i0 = 4 * (p >> 1) + (p & 1);   // first output row of the pair
    const int i  = i0 + 2 * l;               // this wave's output row

    // ---- zero pad columns (both buffers) ----
    for (int e = t; e < 2 * TROWS * 8 * CHUNK; e += 512) {
        int s    = e;
        int bufi = s >= TROWS * 8 * CHUNK;
        if (bufi) s -= TROWS * 8 * CHUNK;
        int r  = s >> 8;
        int pc = (s >> 5) & 7;
        int c  = s & 31;
        int col = (pc < 4) ? pc : 128 + pc;
        xs[bufi][(r * COLS + col) * CHUNK + c] = 0;
    }
    // ---- zero out-of-bounds row planes (both buffers; never re-written) ----
    for (int r = 0; r < TROWS; ++r) {
        int row = i0 + 2 * r - 4;
        if ((unsigned)row >= HH) {
            for (int e = t; e < 128 * CHUNK; e += 512) {
                xs[0][(r * COLS + 4) * CHUNK + e] = 0;
                xs[1][(r * COLS + 4) * CHUNK + e] = 0;
            }
        }
    }

    // ---- accumulators init = bias ----
    const float* bias = (g == 0) ? b0 : (g == 1) ? b1 : (g == 2) ? b2 : b3;
    f32x4 acc[4][8];
#pragma unroll
    for (int mb = 0; mb < 4; ++mb) {
        f32x4 bv;
#pragma unroll
        for (int rr = 0; rr < 4; ++rr) bv[rr] = bias[mb * 16 + h * 4 + rr];
#pragma unroll
        for (int nb = 0; nb < 8; ++nb) acc[mb][nb] = bv;
    }

    const ushort* wg = wp + (size_t)g * WPG;
    const size_t pbase = (size_t)b * 128 * 8;   // plane index base for this batch

    // ---- STAGE: copy 6 swizzled planes into buffer sel via global_load_lds ----
    auto stage = [&](int cc, int sel) {
#pragma unroll
        for (int r = 0; r < TROWS; ++r) {
            int row = i0 + 2 * r - 4;
            if ((unsigned)row < HH) {
                const ushort* gsrc = xt + (pbase + (size_t)row * 8 + cc) * 4096
                                        + wid * 512 + lane * 8;
                const short* ldst = &xs[sel][(r * COLS + 4) * CHUNK + wid * 512];
                gll16(gsrc, ldst);
            }
        }
    };

    stage(0, 0);

    // A-fragment base for this lane: s-th K-step block is wl + s*2048
    const ushort* wl = wg + m16 * 32 + h * 8;
    bf16x8 a_cur[4], a_nxt[4];
#pragma unroll
    for (int mb = 0; mb < 4; ++mb)
        a_cur[mb] = *(const bf16x8*)(wl + mb * 512);

    __syncthreads();    // drains vmcnt(0): buf0 ready, zeros published

    for (int cc = 0; cc < NCHUNK; ++cc) {
        const int sel = cc & 1;
        if (cc < NCHUNK - 1) stage(cc + 1, sel ^ 1);   // issue loads first (T3)

        const short* xsel = xs[sel];
#pragma unroll
        for (int k = 0; k < 5; ++k) {
            int s = cc * 5 + k;
            if (s < 39) {        // prefetch next K-step's A (crosses chunk bdry)
                const ushort* wk1 = wl + (size_t)(s + 1) * 2048;
#pragma unroll
                for (int mb = 0; mb < 4; ++mb)
                    a_nxt[mb] = *(const bf16x8*)(wk1 + mb * 512);
            }
            int rbase = (g == 0) ? 2 : (g == 3 ? 4 - k : k);
            int r  = rbase + l;
            int dj = (g == 1) ? 0 : (g == 2 ? 4 - 2 * k : 2 * k - 4);
            int col0 = m16 + dj + 4;
            int sl   = h ^ ((col0 >> 2) & 3);
            int base = (r * COLS + col0) * CHUNK + sl * 8;
            base ^= ((col0 >> 4) & 1) << 5;
#pragma unroll
            for (int nb = 0; nb < 8; ++nb) {
                int idx = (base + nb * 16 * CHUNK) ^ ((nb & 1) << 5);
                bf16x8 bf = *(const bf16x8*)(&xsel[idx]);
#pragma unroll
                for (int mb = 0; mb < 4; ++mb)
                    acc[mb][nb] = __builtin_amdgcn_mfma_f32_16x16x32_bf16(
                        a_cur[mb], bf, acc[mb][nb], 0, 0, 0);
            }
            if (s < 39) {
#pragma unroll
                for (int mb = 0; mb < 4; ++mb) a_cur[mb] = a_nxt[mb];
            }
        }
        __syncthreads();   // implicit vmcnt(0): next buffer staged & published
    }

    // ---- epilogue: D[m][n], m = mb*16 + h*4 + rr (oc), n = nb*16 + m16 (col) ----
    size_t obase = (((size_t)b * 256 + g * 64) * HH + i) * WW;
#pragma unroll
    for (int mb = 0; mb < 4; ++mb)
#pragma unroll
        for (int rr = 0; rr < 4; ++rr) {
            float* op = out + obase + (size_t)(mb * 16 + h * 4 + rr) * HH * WW + m16;
#pragma unroll
            for (int nb = 0; nb < 8; ++nb)
                op[nb * 16] = acc[mb][nb][rr];
        }
}

// ---------------- fallback (round-3 kernel) if ws too small ----------------
#define XS_ELEMS (5*COLS*CHUNK)
__global__ void repack_w_fb(const float* __restrict__ w0, const float* __restrict__ w1,
                            const float* __restrict__ w2, const float* __restrict__ w3,
                            ushort* __restrict__ wp) {
    int idx = blockIdx.x * 256 + threadIdx.x;
    int g   = idx / WPG;
    int rem = idx - g * WPG;
    int s   = rem >> 11;
    int r2  = rem & 2047;
    int m   = r2 >> 5;
    int kk  = r2 & 31;
    int k   = s % 5;
    int cg  = s / 5;
    const float* w = (g == 0) ? w0 : (g == 1) ? w1 : (g == 2) ? w2 : w3;
    wp[idx] = f2bf(w[(m * CIN + cg * 32 + kk) * 5 + k]);
}

__global__ __launch_bounds__(256, 4)
void asterisk_mfma_fb(const float* __restrict__ x,
                      const ushort* __restrict__ wp,
                      const float* __restrict__ b0, const float* __restrict__ b1,
                      const float* __restrict__ b2, const float* __restrict__ b3,
                      float* __restrict__ out) {
    __shared__ __align__(16) short xs[XS_ELEMS];
    const int t    = threadIdx.x;
    const int lane = t & 63;
    const int wid  = t >> 6;
    const int m16  = lane & 15;
    const int h    = lane >> 4;
    int id = blockIdx.x;
    int sw = (id & 7) * 128 + (id >> 3);
    const int b = sw >> 7;
    const int i = sw & 127;
    for (int e = t; e < 5 * 8 * CHUNK; e += 256) {
        int r  = e >> 8;
        int pc = (e >> 5) & 7;
        int c  = e & 31;
        int col = (pc < 4) ? pc : 128 + pc;
        xs[(r * COLS + col) * CHUNK + c] = 0;
    }
    for (int r = 0; r < 5; ++r) {
        int row = i + 2 * r - 4;
        if ((unsigned)row >= HH)
            for (int e = t; e < COLS * CHUNK; e += 256)
                xs[r * COLS * CHUNK + e] = 0;
    }
    const float* bias = (wid == 0) ? b0 : (wid == 1) ? b1 : (wid == 2) ? b2 : b3;
    f32x4 acc[4][8];
#pragma unroll
    for (int mb = 0; mb < 4; ++mb) {
        f32x4 bv;
#pragma unroll
        for (int rr = 0; rr < 4; ++rr) bv[rr] = bias[mb * 16 + h * 4 + rr];
#pragma unroll
        for (int nb = 0; nb < 8; ++nb) acc[mb][nb] = bv;
    }
    const int cg = t >> 5;
    const int q  = t & 31;
    const float* xb = x + (size_t)b * CIN * HH * WW;
    const ushort* wg = wp + (size_t)wid * WPG;
    for (int cc = 0; cc < NCHUNK; ++cc) {
        __syncthreads();
        {
            int c0 = cc * CHUNK + cg * 4;
            int slot = cg >> 1;
            int sub  = (cg & 1) * 4;
            const float* srcc = xb + (size_t)c0 * HH * WW + q * 4;
#pragma unroll
            for (int r = 0; r < 5; ++r) {
                int row = i + 2 * r - 4;
                if ((unsigned)row < HH) {
                    const float* src = srcc + (size_t)row * WW;
                    float4 v0 = *(const float4*)(src);
                    float4 v1 = *(const float4*)(src + HH * WW);
                    float4 v2 = *(const float4*)(src + 2 * HH * WW);
                    float4 v3 = *(const float4*)(src + 3 * HH * WW);
#pragma unroll
                    for (int jj = 0; jj < 4; ++jj) {
                        int col = q * 4 + 4 + jj;
                        int sl  = slot ^ ((col >> 2) & 3);
                        float f0 = ((const float*)&v0)[jj];
                        float f1 = ((const float*)&v1)[jj];
                        float f2 = ((const float*)&v2)[jj];
                        float f3 = ((const float*)&v3)[jj];
                        __hip_bfloat162 lo = __float22bfloat162_rn(make_float2(f0, f1));
                        __hip_bfloat162 hi = __float22bfloat162_rn(make_float2(f2, f3));
                        uint2 pk;
                        pk.x = *(unsigned*)&lo;
                        pk.y = *(unsigned*)&hi;
                        int wi = (r * COLS + col) * CHUNK + sl * 8 + sub;
                        wi ^= ((col >> 4) & 1) << 5;
                        *(uint2*)&xs[wi] = pk;
                    }
                }
            }
        }
        __syncthreads();
        const ushort* wc = wg + (size_t)(cc * 5 * 64 * 32) + m16 * 32 + h * 8;
        bf16x8 a_cur[4], a_nxt[4];
#pragma unroll
        for (int mb = 0; mb < 4; ++mb)
            a_cur[mb] = *(const bf16x8*)(wc + mb * 16 * 32);
#pragma unroll
        for (int k = 0; k < 5; ++k) {
            if (k < 4) {
                const ushort* wk1 = wc + (size_t)(k + 1) * 64 * 32;
#pragma unroll
                for (int mb = 0; mb < 4; ++mb)
                    a_nxt[mb] = *(const bf16x8*)(wk1 + mb * 16 * 32);
            }
            int r  = (wid == 0) ? 2 : (wid == 3 ? 4 - k : k);
            int dj = (wid == 1) ? 0 : (wid == 2 ? 4 - 2 * k : 2 * k - 4);
            int col0 = m16 + dj + 4;
            int sl   = h ^ ((col0 >> 2) & 3);
            int base = (r * COLS + col0) * CHUNK + sl * 8;
            base ^= ((col0 >> 4) & 1) << 5;
#pragma unroll
            for (int nb = 0; nb < 8; ++nb) {
                int idx = (base + nb * 16 * CHUNK) ^ ((nb & 1) << 5);
                bf16x8 bf = *(const bf16x8*)(&xs[idx]);
#pragma unroll
                for (int mb = 0; mb < 4; ++mb)
                    acc[mb][nb] = __builtin_amdgcn_mfma_f32_16x16x32_bf16(
                        a_cur[mb], bf, acc[mb][nb], 0, 0, 0);
            }
            if (k < 4) {
#pragma unroll
                for (int mb = 0; mb < 4; ++mb) a_cur[mb] = a_nxt[mb];
            }
        }
    }
    size_t obase = (((size_t)b * 256 + wid * 64) * HH + i) * WW;
#pragma unroll
    for (int mb = 0; mb < 4; ++mb)
#pragma unroll
        for (int rr = 0; rr < 4; ++rr) {
            float* op = out + obase + (size_t)(mb * 16 + h * 4 + rr) * HH * WW + m16;
#pragma unroll
            for (int nb = 0; nb < 8; ++nb)
                op[nb * 16] = acc[mb][nb][rr];
        }
}

extern "C" void kernel_launch(void* const* d_in, const int* in_sizes, int n_in,
                              void* d_out, int out_size, void* d_ws, size_t ws_size,
                              hipStream_t stream) {
    const float* x    = (const float*)d_in[0];
    const float* w_h  = (const float*)d_in[1];
    const float* b_h  = (const float*)d_in[2];
    const float* w_v  = (const float*)d_in[3];
    const float* b_v  = (const float*)d_in[4];
    const float* w_d1 = (const float*)d_in[5];
    const float* b_d1 = (const float*)d_in[6];
    const float* w_d2 = (const float*)d_in[7];
    const float* b_d2 = (const float*)d_in[8];
    float* out = (float*)d_out;
    ushort* wpack = (ushort*)d_ws;

    if (ws_size >= (size_t)XT_OFF + (size_t)XT_BYTES) {
        ushort* xt = (ushort*)((char*)d_ws + XT_OFF);
        prep_all<<<PREP_BLOCKS + REPACK_BLOCKS, 256, 0, stream>>>(
            x, w_h, w_v, w_d1, w_d2, wpack, xt);
        asterisk_mfma2<<<512, 512, 0, stream>>>(xt, wpack, b_h, b_v, b_d1, b_d2, out);
    } else {
        repack_w_fb<<<1280, 256, 0, stream>>>(w_h, w_v, w_d1, w_d2, wpack);
        asterisk_mfma_fb<<<1024, 256, 0, stream>>>(x, wpack, b_h, b_v, b_d1, b_d2, out);
    }
}